// Round 10
// baseline (224.663 us; speedup 1.0000x reference)
//
#include <hip/hip_runtime.h>
#include <math.h>

#define C 28   // channels == dim_head == rank
#define N 64   // tokens per window (8x8)

typedef float ff2 __attribute__((ext_vector_type(2)));

// LDS layout (float offsets). 3008 floats = 12032 B -> 13 blocks/CU (26 waves).
// Phase 1: QT [28][64] @0..1792 (FULL), KTH [16][64] @1792..2816 (K d-half
//          buffer: d0..15 staged up front, d16..27 re-staged from regs after
//          sim half 1). Both dead after B2.
// Phase 2: A = per-wave QUARTER [16 j][32 i] @ 512*wv (overlay QT head),
//          staged 4x interleaved with AV quarters (in-wave ordering only).
//          V [64][28] @1024..2816 (overlays QT tail + KTH; written after B2).
//          OT = per-wave [32][28] @ 896*wv (overlays A+V head, after B4).
// Scalars SQ/SGK/TH at 2816+ (never overlaid).
#define QT_OFF  0
#define KTH_OFF 1792
#define A_OFF   0
#define V_OFF   1024
#define OT_OFF  0
#define SQ_OFF  2816
#define SGK_OFF 2880
#define TH_OFF  2944
#define LDS_FLOATS 3008

// Exact ascending 8-lane-group prefix sum via DPP row_shr:1 (VALU-only).
// Lane gb+7 holds the fully left-nested ascending sum (validated R6-R9).
__device__ __forceinline__ float prefix8_asc(float s) {
    float p = s;
    #pragma unroll
    for (int k = 0; k < 7; ++k) {
        int sh = __builtin_amdgcn_update_dpp(0, __float_as_int(p),
                                             0x111 /*row_shr:1*/, 0xF, 0xF, true);
        p = __int_as_float(sh) + s;
    }
    return p;
}

// Max over each 8-lane group, VALU-only (validated R8/R9).
__device__ __forceinline__ float max8_dpp(float m) {
    int t;
    t = __builtin_amdgcn_update_dpp(0, __float_as_int(m), 0xB1,  0xF, 0xF, true);
    m = fmaxf(m, __int_as_float(t));
    t = __builtin_amdgcn_update_dpp(0, __float_as_int(m), 0x4E,  0xF, 0xF, true);
    m = fmaxf(m, __int_as_float(t));
    t = __builtin_amdgcn_update_dpp(0, __float_as_int(m), 0x141, 0xF, 0xF, true);
    m = fmaxf(m, __int_as_float(t));
    return m;
}

__global__ __launch_bounds__(128, 8)   // hard-pin VGPR <= 64 (wave-slot granule)
void fa_tiled(const float* __restrict__ x,
              const float* __restrict__ Wqk,   // [56][28]
              const float* __restrict__ Wv,    // [28][28]
              const float* __restrict__ Wout,  // [28][28]
              const float* __restrict__ bout,  // [28]
              const float* __restrict__ Wpcq,  // [28]
              const float* __restrict__ bpcq,  // [1]
              const float* __restrict__ Wpck,  // [28]
              const float* __restrict__ bpck,  // [1]
              const float* __restrict__ Wm1,   // [64]
              const float* __restrict__ Wm2a,  // [64][64]
              const float* __restrict__ Wm2b,  // [64]
              float* __restrict__ out)
{
    __shared__ float S[LDS_FLOATS];

    const int tid = threadIdx.x;       // 0..127 (2 waves per problem)
    const int wv  = tid >> 6;          // wave id: 0 -> q-side, 1 -> k-side
    const int ln  = tid & 63;          // lane in wave == token id in phase A
    const int pid = blockIdx.x;        // 0..8191, one block per problem
    const int win = pid >> 3;
    const int Bi  = pid & 7;
    const int hw = win >> 5, ww = win & 31;
    const int b0 = ln >> 3, b1 = ln & 7;
    const size_t base = ((((size_t)Bi * 256) + (size_t)(hw * 8 + b0)) * 256
                         + (size_t)(ww * 8 + b1)) * C;

    // sim tile coords: 4 rows x 8 cols per lane
    const int ti = tid >> 3;           // 0..15 (global row group)
    const int tj = tid & 7;            // 0..7  (col group, j = 8*tj+cc)
    const int rg = ti & 7;             // wave-local row group 0..7
    const int gb = ln & 56;            // in-wave base of this lane's tj-group

    // Register union: wave0 uses st[0..15] = vv d0..15.
    // wave1 uses st[0..11] = vv d16..27, st[12..23] = k values d16..27 (kh).
    float st[24];

    // ========== Phase A: projections; xr dies here ==========================
    {
        float xr[C];
        {
            const float4* p = (const float4*)(x + base);
            #pragma unroll
            for (int i = 0; i < 7; ++i) {
                float4 t = p[i];
                xr[4*i+0] = t.x; xr[4*i+1] = t.y; xr[4*i+2] = t.z; xr[4*i+3] = t.w;
            }
        }

        if (wv == 0) {
            // q -> QT FULL (transposed), sig_q (R9-validated ff2 chains)
            ff2 sq2 = {0.f, 0.f};
            #pragma unroll 2
            for (int d4 = 0; d4 < 7; ++d4) {
                float qq[4];
                #pragma unroll
                for (int t = 0; t < 4; ++t) {
                    const int d = 4*d4 + t;
                    ff2 a = {0.f, 0.f};
                    #pragma unroll
                    for (int c = 0; c < C; c += 2) {
                        ff2 w = *(const ff2*)&Wqk[d*C + c];
                        ff2 xv; xv.x = xr[c]; xv.y = xr[c+1];
                        a += w * xv;
                    }
                    qq[t] = a.x + a.y;
                    S[QT_OFF + d*64 + ln] = qq[t];
                }
                ff2 q01; q01.x = qq[0]; q01.y = qq[1];
                ff2 q23; q23.x = qq[2]; q23.y = qq[3];
                ff2 w01 = *(const ff2*)&Wpcq[4*d4];
                ff2 w23 = *(const ff2*)&Wpcq[4*d4+2];
                sq2 += q01 * w01;
                sq2 += q23 * w23;
            }
            S[SQ_OFF + ln] = sq2.x + sq2.y + bpcq[0];
            // vv d = 0..15 into st[0..15]
            #pragma unroll
            for (int d4 = 0; d4 < 4; ++d4) {
                #pragma unroll
                for (int t = 0; t < 4; ++t) {
                    const int d = 4*d4 + t;
                    ff2 a = {0.f, 0.f};
                    #pragma unroll
                    for (int c = 0; c < C; c += 2) {
                        ff2 w = *(const ff2*)&Wv[d*C + c];
                        ff2 xv; xv.x = xr[c]; xv.y = xr[c+1];
                        a += w * xv;
                    }
                    st[4*d4+t] = a.x + a.y;
                }
            }
        } else {
            // k: d0..15 staged to KTH, d16..27 kept in st[12..23].
            // ak chain scalar-sequential over d4 0..6 (mask-sensitive, exact).
            float ak = 0.f;
            #pragma unroll
            for (int d4 = 0; d4 < 4; ++d4) {
                float kk[4];
                #pragma unroll
                for (int t = 0; t < 4; ++t) {
                    const int d = 4*d4 + t;
                    ff2 a = {0.f, 0.f};
                    #pragma unroll
                    for (int c = 0; c < C; c += 2) {
                        ff2 w = *(const ff2*)&Wqk[(C+d)*C + c];
                        ff2 xv; xv.x = xr[c]; xv.y = xr[c+1];
                        a += w * xv;
                    }
                    kk[t] = a.x + a.y;
                    S[KTH_OFF + d*64 + ln] = kk[t];
                }
                ak += kk[0] * Wpck[4*d4+0];
                ak += kk[1] * Wpck[4*d4+1];
                ak += kk[2] * Wpck[4*d4+2];
                ak += kk[3] * Wpck[4*d4+3];
            }
            #pragma unroll
            for (int d4 = 4; d4 < 7; ++d4) {
                float kk[4];
                #pragma unroll
                for (int t = 0; t < 4; ++t) {
                    const int d = 4*d4 + t;
                    ff2 a = {0.f, 0.f};
                    #pragma unroll
                    for (int c = 0; c < C; c += 2) {
                        ff2 w = *(const ff2*)&Wqk[(C+d)*C + c];
                        ff2 xv; xv.x = xr[c]; xv.y = xr[c+1];
                        a += w * xv;
                    }
                    kk[t] = a.x + a.y;
                    st[12 + 4*(d4-4) + t] = kk[t];
                }
                ak += kk[0] * Wpck[4*d4+0];
                ak += kk[1] * Wpck[4*d4+1];
                ak += kk[2] * Wpck[4*d4+2];
                ak += kk[3] * Wpck[4*d4+3];
            }
            S[SGK_OFF + ln] = ak + bpck[0];
            // vv d = 16..27 into st[0..11]
            #pragma unroll
            for (int d4 = 4; d4 < 7; ++d4) {
                #pragma unroll
                for (int t = 0; t < 4; ++t) {
                    const int d = 4*d4 + t;
                    ff2 a = {0.f, 0.f};
                    #pragma unroll
                    for (int c = 0; c < C; c += 2) {
                        ff2 w = *(const ff2*)&Wv[d*C + c];
                        ff2 xv; xv.x = xr[c]; xv.y = xr[c+1];
                        a += w * xv;
                    }
                    st[4*(d4-4)+t] = a.x + a.y;
                }
            }
        }
    }
    __syncthreads();   // B1a: QT full, KTH(d0..15), SQ, SGK ready

    // ====== sim half 1: d 0..15 (ff2 row-pairs, R9-validated) ===============
    ff2 acc2[8][2];    // acc2[cc][p][e] = sraw[4ti + 2p+e][8tj+cc]
    #pragma unroll
    for (int cc = 0; cc < 8; ++cc) {
        acc2[cc][0] = (ff2){0.f, 0.f};
        acc2[cc][1] = (ff2){0.f, 0.f};
    }

    #pragma unroll 2
    for (int d = 0; d < 16; ++d) {
        float4 qa = *(const float4*)&S[QT_OFF + d*64 + 4*ti];
        float4 ka = *(const float4*)&S[KTH_OFF + d*64 + 8*tj];
        float4 kb = *(const float4*)&S[KTH_OFF + d*64 + 8*tj + 4];
        ff2 q0; q0.x = qa.x; q0.y = qa.y;
        ff2 q1; q1.x = qa.z; q1.y = qa.w;
        float k8[8] = {ka.x,ka.y,ka.z,ka.w,kb.x,kb.y,kb.z,kb.w};
        #pragma unroll
        for (int cc = 0; cc < 8; ++cc) {
            ff2 ks; ks.x = k8[cc]; ks.y = k8[cc];
            acc2[cc][0] += q0 * ks;
            acc2[cc][1] += q1 * ks;
        }
    }
    __syncthreads();   // B1b: all sim-half1 KTH reads done

    // ---- re-stage K d16..27 from regs into KTH rows 0..11 ----
    if (wv == 1) {
        #pragma unroll
        for (int dl = 0; dl < 12; ++dl)
            S[KTH_OFF + dl*64 + ln] = st[12 + dl];
    }
    __syncthreads();   // B1c: KTH(d16..27) ready

    // ====== sim half 2: d 16..27 ============================================
    #pragma unroll 2
    for (int d = 16; d < 28; ++d) {
        float4 qa = *(const float4*)&S[QT_OFF + d*64 + 4*ti];
        float4 ka = *(const float4*)&S[KTH_OFF + (d-16)*64 + 8*tj];
        float4 kb = *(const float4*)&S[KTH_OFF + (d-16)*64 + 8*tj + 4];
        ff2 q0; q0.x = qa.x; q0.y = qa.y;
        ff2 q1; q1.x = qa.z; q1.y = qa.w;
        float k8[8] = {ka.x,ka.y,ka.z,ka.w,kb.x,kb.y,kb.z,kb.w};
        #pragma unroll
        for (int cc = 0; cc < 8; ++cc) {
            ff2 ks; ks.x = k8[cc]; ks.y = k8[cc];
            acc2[cc][0] += q0 * ks;
            acc2[cc][1] += q1 * ks;
        }
    }

    // ---- theta partials (strict ascending j; diag excluded), DPP prefix ----
    {
        float4 wa = *(const float4*)&Wm1[8*tj];
        float4 wb = *(const float4*)&Wm1[8*tj + 4];
        float w8[8] = {wa.x,wa.y,wa.z,wa.w,wb.x,wb.y,wb.z,wb.w};
        const bool e0 = (4*ti == 8*tj);          // diag at cc == rr
        const bool e4 = (4*ti - 8*tj == 4);      // diag at cc == rr+4
        float th4[4];
        #pragma unroll
        for (int rr = 0; rr < 4; ++rr) {
            float s = 0.f;
            #pragma unroll
            for (int cc = 0; cc < 8; ++cc) {
                float av = acc2[cc][rr >> 1][rr & 1];
                float term = av * w8[cc];
                if (cc == rr     && e0) term = 0.f;
                if (cc == rr + 4 && e4) term = 0.f;
                s += term;
            }
            th4[rr] = prefix8_asc(s);
        }
        if (tj == 7)
            *(float4*)&S[TH_OFF + 4*ti] =
                make_float4(th4[0], th4[1], th4[2], th4[3]);
    }
    __syncthreads();   // B2: QT/KTH dead, TH complete

    // ---- V write (full, from st regs; overlays QT tail + KTH) --------------
    if (wv == 0) {
        *(float4*)&S[V_OFF + ln*C +  0] = make_float4(st[0], st[1], st[2], st[3]);
        *(float4*)&S[V_OFF + ln*C +  4] = make_float4(st[4], st[5], st[6], st[7]);
        *(float4*)&S[V_OFF + ln*C +  8] = make_float4(st[8], st[9], st[10],st[11]);
        *(float4*)&S[V_OFF + ln*C + 12] = make_float4(st[12],st[13],st[14],st[15]);
    } else {
        *(float4*)&S[V_OFF + ln*C + 16] = make_float4(st[0], st[1], st[2], st[3]);
        *(float4*)&S[V_OFF + ln*C + 20] = make_float4(st[4], st[5], st[6], st[7]);
        *(float4*)&S[V_OFF + ln*C + 24] = make_float4(st[8], st[9], st[10],st[11]);
    }

    // ---- MLP2 (R9-validated ff2; both waves redundantly -> identical theta) -
    float theta;
    {
        const float* wrow = Wm2a + ln * N;
        ff2 A = {0.f, 0.f}, B = {0.f, 0.f};
        #pragma unroll 4
        for (int i4 = 0; i4 < 16; ++i4) {
            float4 t4 = *(const float4*)&S[TH_OFF + 4*i4];
            float4 w4 = *(const float4*)&wrow[4*i4];
            ff2 tl; tl.x = t4.x; tl.y = t4.y;
            ff2 th; th.x = t4.z; th.y = t4.w;
            ff2 wl; wl.x = w4.x; wl.y = w4.y;
            ff2 wh; wh.x = w4.z; wh.y = w4.w;
            A += tl * wl;
            B += th * wh;
        }
        float t = (A.x + A.y) + (B.x + B.y);
        t = (t >= 0.f) ? t : 0.1f * t;
        theta = t * Wm2b[ln];
        #pragma unroll
        for (int off = 32; off > 0; off >>= 1)
            theta += __shfl_xor(theta, off, 64);
    }

    // ---- Sigma scale (order matches: (sraw*sq)*sgk), element-wise exact -----
    {
        float4 a = *(const float4*)&S[SQ_OFF + 4*ti];
        ff2 sq0; sq0.x = a.x; sq0.y = a.y;
        ff2 sq1; sq1.x = a.z; sq1.y = a.w;
        float4 c0 = *(const float4*)&S[SGK_OFF + 8*tj];
        float4 c1 = *(const float4*)&S[SGK_OFF + 8*tj + 4];
        float sg8[8] = {c0.x,c0.y,c0.z,c0.w,c1.x,c1.y,c1.z,c1.w};
        #pragma unroll
        for (int cc = 0; cc < 8; ++cc) {
            ff2 gs; gs.x = sg8[cc]; gs.y = sg8[cc];
            acc2[cc][0] = (acc2[cc][0] * sq0) * gs;
            acc2[cc][1] = (acc2[cc][1] * sq1) * gs;
        }
    }

    // ---- row max (DPP), exp, Z (DPP prefix), mask (all in regs) ------------
    float m4[4];
    #pragma unroll
    for (int rr = 0; rr < 4; ++rr) {
        float mp = -1e30f;
        #pragma unroll
        for (int cc = 0; cc < 8; ++cc) mp = fmaxf(mp, acc2[cc][rr >> 1][rr & 1]);
        m4[rr] = max8_dpp(mp);
    }
    float z4[4];
    #pragma unroll
    for (int rr = 0; rr < 4; ++rr) {
        float zp = 0.f;
        #pragma unroll
        for (int cc = 0; cc < 8; ++cc) {
            float ss = acc2[cc][rr >> 1][rr & 1];
            float e = __expf(ss - m4[rr]);
            zp += e;
            acc2[cc][rr >> 1][rr & 1] = (ss > theta) ? e : 0.f;
        }
        float zpre = prefix8_asc(zp);
        z4[rr] = __shfl(zpre, gb + 7, 64);
    }

    // ---- stage A quarter 0 (cols j 0..15) into own [16 j][32 i] region -----
    // Writers: tj in {0,1}. rot = 4*(jq>>3): the two tj-groups land on the same
    // bank-start set -> 2-way, which is free (m136).
    float* Aw = &S[A_OFF + 512*wv];
    if ((tj >> 1) == 0) {
        #pragma unroll
        for (int cc = 0; cc < 8; ++cc) {
            const int jq = 8*(tj & 1) + cc;
            *(float4*)&Aw[jq*32 + ((4*rg + 4*(jq >> 3)) & 31)] =
                make_float4(acc2[cc][0].x, acc2[cc][0].y, acc2[cc][1].x, acc2[cc][1].y);
        }
    }
    __syncthreads();   // B3: V complete (cross-wave); A quarter-0 staged

    // ============ AV: lane = (rg, dg); 4 quarters, strict ascending j =======
    const int dg  = tj;
    const int dgc = (dg < 7) ? dg : 6;   // dg==7 duplicates dg==6, write masked
    ff2 pv[4][2];
    #pragma unroll
    for (int rr = 0; rr < 4; ++rr) {
        pv[rr][0] = (ff2){0.f, 0.f};
        pv[rr][1] = (ff2){0.f, 0.f};
    }

    #pragma unroll
    for (int q = 0; q < 4; ++q) {
        // AV over quarter q (j = 16q .. 16q+15), ascending
        #pragma unroll 8
        for (int jq = 0; jq < 16; ++jq) {
            float4 a4 = *(const float4*)&Aw[jq*32 + ((4*rg + 4*(jq >> 3)) & 31)];
            float4 v4 = *(const float4*)&S[V_OFF + (16*q + jq)*C + 4*dgc];
            ff2 vlo; vlo.x = v4.x; vlo.y = v4.y;
            ff2 vhi; vhi.x = v4.z; vhi.y = v4.w;
            float a8[4] = {a4.x, a4.y, a4.z, a4.w};
            #pragma unroll
            for (int rr = 0; rr < 4; ++rr) {
                ff2 as; as.x = a8[rr]; as.y = a8[rr];
                pv[rr][0] += as * vlo;
                pv[rr][1] += as * vhi;
            }
        }
        // stage next quarter (in-wave ordering: own region, own reads done)
        if (q < 3 && (tj >> 1) == q + 1) {
            #pragma unroll
            for (int cc = 0; cc < 8; ++cc) {
                const int jq = 8*(tj & 1) + cc;
                *(float4*)&Aw[jq*32 + ((4*rg + 4*(jq >> 3)) & 31)] =
                    make_float4(acc2[cc][0].x, acc2[cc][0].y, acc2[cc][1].x, acc2[cc][1].y);
            }
        }
    }

    // normalize by Z (exact 1.0f/Z divide; z4 lives in this lane)
    #pragma unroll
    for (int rr = 0; rr < 4; ++rr) {
        float rz = 1.0f / z4[rr];
        ff2 rz2; rz2.x = rz; rz2.y = rz;
        pv[rr][0] *= rz2;
        pv[rr][1] *= rz2;
    }
    __syncthreads();   // B4: all AV reads (A own-wave, V cross-wave) done

    // ---- OT: per-wave [32][28] @ 896*wv (overlays A + V head) --------------
    if (dg < 7) {
        #pragma unroll
        for (int rr = 0; rr < 4; ++rr)
            *(float4*)&S[OT_OFF + 896*wv + (4*rg+rr)*C + 4*dg] =
                make_float4(pv[rr][0].x, pv[rr][0].y, pv[rr][1].x, pv[rr][1].y);
    }
    // No barrier: epilogue reads only THIS wave's OT (in-wave DS ordering,
    // same pattern as the A-staging -> AV reads used since R3).

    // ====== epilogue: wave-local. lane = (token in own 32 rows, e-half) =====
    const int tk  = ln & 31;
    const int eh  = ln >> 5;
    const int tok = 32*wv + tk;
    const int ob0 = tok >> 3, ob1 = tok & 7;
    const size_t obase = ((((size_t)Bi * 256) + (size_t)(hw * 8 + ob0)) * 256
                          + (size_t)(ww * 8 + ob1)) * C;
    float o[C];
    {
        const float* orow = &S[OT_OFF + 896*wv + tk*C];
        #pragma unroll
        for (int i = 0; i < 7; ++i) {
            float4 t = *(const float4*)(orow + 4*i);
            o[4*i+0] = t.x; o[4*i+1] = t.y; o[4*i+2] = t.z; o[4*i+3] = t.w;
        }
    }
    if (eh == 0) {       // e = 0..15
        float y[16];
        #pragma unroll 2
        for (int e4 = 0; e4 < 4; ++e4) {
            #pragma unroll
            for (int t = 0; t < 4; ++t) {
                const int e = 4*e4 + t;
                ff2 a = {0.f, 0.f};
                #pragma unroll
                for (int d = 0; d < C; d += 2) {
                    ff2 w = *(const ff2*)&Wout[e*C + d];
                    ff2 ov; ov.x = o[d]; ov.y = o[d+1];
                    a += w * ov;
                }
                y[e] = (a.x + a.y) + bout[e];
            }
        }
        float4* yp = (float4*)(out + obase);
        #pragma unroll
        for (int i = 0; i < 4; ++i)
            yp[i] = make_float4(y[4*i+0], y[4*i+1], y[4*i+2], y[4*i+3]);
    } else {             // e = 16..27
        float y[12];
        #pragma unroll 2
        for (int e4 = 0; e4 < 3; ++e4) {
            #pragma unroll
            for (int t = 0; t < 4; ++t) {
                const int e = 16 + 4*e4 + t;
                ff2 a = {0.f, 0.f};
                #pragma unroll
                for (int d = 0; d < C; d += 2) {
                    ff2 w = *(const ff2*)&Wout[e*C + d];
                    ff2 ov; ov.x = o[d]; ov.y = o[d+1];
                    a += w * ov;
                }
                y[4*e4+t] = (a.x + a.y) + bout[e];
            }
        }
        float4* yp = (float4*)(out + obase + 16);
        #pragma unroll
        for (int i = 0; i < 3; ++i)
            yp[i] = make_float4(y[4*i+0], y[4*i+1], y[4*i+2], y[4*i+3]);
    }
}

extern "C" void kernel_launch(void* const* d_in, const int* in_sizes, int n_in,
                              void* d_out, int out_size, void* d_ws, size_t ws_size,
                              hipStream_t stream) {
    const float* x     = (const float*)d_in[0];
    const float* W_qk  = (const float*)d_in[1];
    const float* W_v   = (const float*)d_in[2];
    const float* W_out = (const float*)d_in[3];
    const float* b_out = (const float*)d_in[4];
    const float* W_pcq = (const float*)d_in[5];
    const float* b_pcq = (const float*)d_in[6];
    const float* W_pck = (const float*)d_in[7];
    const float* b_pck = (const float*)d_in[8];
    const float* W_m1  = (const float*)d_in[9];
    const float* W_m2a = (const float*)d_in[10];
    const float* W_m2b = (const float*)d_in[11];
    float* y = (float*)d_out;

    // 8192 problems, one 128-thread (2-wave) block per problem
    hipLaunchKernelGGL(fa_tiled, dim3(8192), dim3(128), 0, stream,
                       x, W_qk, W_v, W_out, b_out, W_pcq, b_pcq,
                       W_pck, b_pck, W_m1, W_m2a, W_m2b, y);
}

// Round 11
// 220.142 us; speedup vs baseline: 1.0205x; 1.0205x over previous
//
#include <hip/hip_runtime.h>
#include <math.h>

#define C 28   // channels == dim_head == rank
#define N 64   // tokens per window (8x8)

typedef float ff2 __attribute__((ext_vector_type(2)));

// LDS layout (float offsets). 4032 floats = 16128 B.
// Phase 1: QT [28][64] @0, KT [28][64] @1792 (dead after B2)
// Phase 2: A = per-wave [32 j][32 i] halves @0/@1024 (overlay QT), staged twice
//          V [64][28] @2048 (overlays dead KT tail; written AFTER B2 from regs)
//          OT = per-wave [32][28] overlays own A after final AV reads; the
//          epilogue is WAVE-LOCAL (reads only own OT) -> no barrier after OT.
// Scalars SQ/SGK/TH at 3840+ (outside all overlay ranges).
#define A_OFF   0
#define QT_OFF  0
#define KT_OFF  1792
#define V_OFF   2048
#define SQ_OFF  3840
#define SGK_OFF 3904
#define TH_OFF  3968
#define LDS_FLOATS 4032

// Exact ascending 8-lane-group prefix sum via DPP row_shr:1 (VALU-only).
// Lane gb+7 holds the fully left-nested ascending sum (validated R6-R10).
__device__ __forceinline__ float prefix8_asc(float s) {
    float p = s;
    #pragma unroll
    for (int k = 0; k < 7; ++k) {
        int sh = __builtin_amdgcn_update_dpp(0, __float_as_int(p),
                                             0x111 /*row_shr:1*/, 0xF, 0xF, true);
        p = __int_as_float(sh) + s;
    }
    return p;
}

// Max over each 8-lane group, VALU-only (validated R8-R10).
__device__ __forceinline__ float max8_dpp(float m) {
    int t;
    t = __builtin_amdgcn_update_dpp(0, __float_as_int(m), 0xB1,  0xF, 0xF, true);
    m = fmaxf(m, __int_as_float(t));
    t = __builtin_amdgcn_update_dpp(0, __float_as_int(m), 0x4E,  0xF, 0xF, true);
    m = fmaxf(m, __int_as_float(t));
    t = __builtin_amdgcn_update_dpp(0, __float_as_int(m), 0x141, 0xF, 0xF, true);
    m = fmaxf(m, __int_as_float(t));
    return m;
}

__global__ __launch_bounds__(128, 8)   // hard-pin VGPR <= 512/8 = 64 (granule)
void fa_tiled(const float* __restrict__ x,
              const float* __restrict__ Wqk,   // [56][28]
              const float* __restrict__ Wv,    // [28][28]
              const float* __restrict__ Wout,  // [28][28]
              const float* __restrict__ bout,  // [28]
              const float* __restrict__ Wpcq,  // [28]
              const float* __restrict__ bpcq,  // [1]
              const float* __restrict__ Wpck,  // [28]
              const float* __restrict__ bpck,  // [1]
              const float* __restrict__ Wm1,   // [64]
              const float* __restrict__ Wm2a,  // [64][64]
              const float* __restrict__ Wm2b,  // [64]
              float* __restrict__ out)
{
    __shared__ float S[LDS_FLOATS];

    const int tid = threadIdx.x;       // 0..127 (2 waves per problem)
    const int wv  = tid >> 6;          // wave id: 0 -> q-side, 1 -> k-side
    const int ln  = tid & 63;          // lane in wave == token id in phase A
    const int pid = blockIdx.x;        // 0..8191, one block per problem
    const int win = pid >> 3;
    const int Bi  = pid & 7;
    const int hw = win >> 5, ww = win & 31;
    const int b0 = ln >> 3, b1 = ln & 7;
    const size_t base = ((((size_t)Bi * 256) + (size_t)(hw * 8 + b0)) * 256
                         + (size_t)(ww * 8 + b1)) * C;

    // sim tile coords: 4 rows x 8 cols per lane
    const int ti = tid >> 3;           // 0..15 (global row group)
    const int tj = tid & 7;            // 0..7  (col group, j = 8*tj+cc)
    const int rg = ti & 7;             // wave-local row group 0..7
    const int gb = ln & 56;            // in-wave base of this lane's tj-group

    float vv[16];                      // deferred V values (wave0:16, wave1:12)

    // ========== Phase A (R9-validated ff2): q/k proj + V-into-regs ==========
    {
        float xr[C];
        {
            const float4* p = (const float4*)(x + base);
            #pragma unroll
            for (int i = 0; i < 7; ++i) {
                float4 t = p[i];
                xr[4*i+0] = t.x; xr[4*i+1] = t.y; xr[4*i+2] = t.z; xr[4*i+3] = t.w;
            }
        }

        if (wv == 0) {
            // q -> QT (transposed), sig_q. ff2 pairs = (even,odd) chains.
            ff2 sq2 = {0.f, 0.f};
            #pragma unroll 2
            for (int d4 = 0; d4 < 7; ++d4) {
                float qq[4];
                #pragma unroll
                for (int t = 0; t < 4; ++t) {
                    const int d = 4*d4 + t;
                    ff2 a = {0.f, 0.f};
                    #pragma unroll
                    for (int c = 0; c < C; c += 2) {
                        ff2 w = *(const ff2*)&Wqk[d*C + c];
                        ff2 xv; xv.x = xr[c]; xv.y = xr[c+1];
                        a += w * xv;
                    }
                    qq[t] = a.x + a.y;
                    S[QT_OFF + d*64 + ln] = qq[t];
                }
                ff2 q01; q01.x = qq[0]; q01.y = qq[1];
                ff2 q23; q23.x = qq[2]; q23.y = qq[3];
                ff2 w01 = *(const ff2*)&Wpcq[4*d4];
                ff2 w23 = *(const ff2*)&Wpcq[4*d4+2];
                sq2 += q01 * w01;
                sq2 += q23 * w23;
            }
            S[SQ_OFF + ln] = sq2.x + sq2.y + bpcq[0];
            // V dims d = 0..15 into regs
            #pragma unroll
            for (int d4 = 0; d4 < 4; ++d4) {
                #pragma unroll
                for (int t = 0; t < 4; ++t) {
                    const int d = 4*d4 + t;
                    ff2 a = {0.f, 0.f};
                    #pragma unroll
                    for (int c = 0; c < C; c += 2) {
                        ff2 w = *(const ff2*)&Wv[d*C + c];
                        ff2 xv; xv.x = xr[c]; xv.y = xr[c+1];
                        a += w * xv;
                    }
                    vv[4*d4+t] = a.x + a.y;
                }
            }
        } else {
            // k -> KT (transposed), sig_k (ak chain scalar-sequential: exact).
            float ak = 0.f;
            #pragma unroll 2
            for (int d4 = 0; d4 < 7; ++d4) {
                float kk[4];
                #pragma unroll
                for (int t = 0; t < 4; ++t) {
                    const int d = 4*d4 + t;
                    ff2 a = {0.f, 0.f};
                    #pragma unroll
                    for (int c = 0; c < C; c += 2) {
                        ff2 w = *(const ff2*)&Wqk[(C+d)*C + c];
                        ff2 xv; xv.x = xr[c]; xv.y = xr[c+1];
                        a += w * xv;
                    }
                    kk[t] = a.x + a.y;
                    S[KT_OFF + d*64 + ln] = kk[t];
                }
                ak += kk[0] * Wpck[4*d4+0];
                ak += kk[1] * Wpck[4*d4+1];
                ak += kk[2] * Wpck[4*d4+2];
                ak += kk[3] * Wpck[4*d4+3];
            }
            S[SGK_OFF + ln] = ak + bpck[0];
            // V dims d = 16..27 into regs
            #pragma unroll
            for (int d4 = 4; d4 < 7; ++d4) {
                #pragma unroll
                for (int t = 0; t < 4; ++t) {
                    const int d = 4*d4 + t;
                    ff2 a = {0.f, 0.f};
                    #pragma unroll
                    for (int c = 0; c < C; c += 2) {
                        ff2 w = *(const ff2*)&Wv[d*C + c];
                        ff2 xv; xv.x = xr[c]; xv.y = xr[c+1];
                        a += w * xv;
                    }
                    vv[4*(d4-4)+t] = a.x + a.y;
                }
            }
        }
    }
    __syncthreads();   // B1: QT, KT, SQ, SGK ready

    // ====== sim: 4x8 tile as ff2 row-pairs (R5/R9-validated, bit-exact) =====
    ff2 acc2[8][2];    // acc2[cc][p][e] = sraw[4ti + 2p+e][8tj+cc]
    #pragma unroll
    for (int cc = 0; cc < 8; ++cc) {
        acc2[cc][0] = (ff2){0.f, 0.f};
        acc2[cc][1] = (ff2){0.f, 0.f};
    }

    #pragma unroll 2
    for (int d = 0; d < C; ++d) {
        float4 qa = *(const float4*)&S[QT_OFF + d*64 + 4*ti];
        float4 ka = *(const float4*)&S[KT_OFF + d*64 + 8*tj];
        float4 kb = *(const float4*)&S[KT_OFF + d*64 + 8*tj + 4];
        ff2 q0; q0.x = qa.x; q0.y = qa.y;
        ff2 q1; q1.x = qa.z; q1.y = qa.w;
        float k8[8] = {ka.x,ka.y,ka.z,ka.w,kb.x,kb.y,kb.z,kb.w};
        #pragma unroll
        for (int cc = 0; cc < 8; ++cc) {
            ff2 ks; ks.x = k8[cc]; ks.y = k8[cc];
            acc2[cc][0] += q0 * ks;
            acc2[cc][1] += q1 * ks;
        }
    }

    // ---- theta partials (strict ascending j per 8-col group; diag excluded),
    //      DPP ascending prefix (exact assoc); lane tj==7 writes all 4 as b128
    {
        float4 wa = *(const float4*)&Wm1[8*tj];
        float4 wb = *(const float4*)&Wm1[8*tj + 4];
        float w8[8] = {wa.x,wa.y,wa.z,wa.w,wb.x,wb.y,wb.z,wb.w};
        const bool e0 = (4*ti == 8*tj);          // diag at cc == rr
        const bool e4 = (4*ti - 8*tj == 4);      // diag at cc == rr+4
        float th4[4];
        #pragma unroll
        for (int rr = 0; rr < 4; ++rr) {
            float s = 0.f;
            #pragma unroll
            for (int cc = 0; cc < 8; ++cc) {
                float av = acc2[cc][rr >> 1][rr & 1];
                float term = av * w8[cc];
                if (cc == rr     && e0) term = 0.f;
                if (cc == rr + 4 && e4) term = 0.f;
                s += term;
            }
            th4[rr] = prefix8_asc(s);
        }
        if (tj == 7)
            *(float4*)&S[TH_OFF + 4*ti] =
                make_float4(th4[0], th4[1], th4[2], th4[3]);
    }
    __syncthreads();   // B2: QT/KT reads done, TH complete

    // ---- V write (deferred; overlays dead KT tail). Cross-wave: B3 guards ----
    if (wv == 0) {
        *(float4*)&S[V_OFF + ln*C +  0] = make_float4(vv[0], vv[1], vv[2], vv[3]);
        *(float4*)&S[V_OFF + ln*C +  4] = make_float4(vv[4], vv[5], vv[6], vv[7]);
        *(float4*)&S[V_OFF + ln*C +  8] = make_float4(vv[8], vv[9], vv[10],vv[11]);
        *(float4*)&S[V_OFF + ln*C + 12] = make_float4(vv[12],vv[13],vv[14],vv[15]);
    } else {
        *(float4*)&S[V_OFF + ln*C + 16] = make_float4(vv[0], vv[1], vv[2], vv[3]);
        *(float4*)&S[V_OFF + ln*C + 20] = make_float4(vv[4], vv[5], vv[6], vv[7]);
        *(float4*)&S[V_OFF + ln*C + 24] = make_float4(vv[8], vv[9], vv[10],vv[11]);
    }

    // ---- MLP2 (R9-validated ff2; both waves redundantly -> identical theta) --
    float theta;
    {
        const float* wrow = Wm2a + ln * N;
        ff2 A = {0.f, 0.f}, B = {0.f, 0.f};
        #pragma unroll 4
        for (int i4 = 0; i4 < 16; ++i4) {
            float4 t4 = *(const float4*)&S[TH_OFF + 4*i4];
            float4 w4 = *(const float4*)&wrow[4*i4];
            ff2 tl; tl.x = t4.x; tl.y = t4.y;
            ff2 th; th.x = t4.z; th.y = t4.w;
            ff2 wl; wl.x = w4.x; wl.y = w4.y;
            ff2 wh; wh.x = w4.z; wh.y = w4.w;
            A += tl * wl;
            B += th * wh;
        }
        float t = (A.x + A.y) + (B.x + B.y);
        t = (t >= 0.f) ? t : 0.1f * t;
        theta = t * Wm2b[ln];
        #pragma unroll
        for (int off = 32; off > 0; off >>= 1)
            theta += __shfl_xor(theta, off, 64);
    }

    // ---- Sigma scale (order matches: (sraw*sq)*sgk), element-wise exact -----
    {
        float4 a = *(const float4*)&S[SQ_OFF + 4*ti];
        ff2 sq0; sq0.x = a.x; sq0.y = a.y;
        ff2 sq1; sq1.x = a.z; sq1.y = a.w;
        float4 c0 = *(const float4*)&S[SGK_OFF + 8*tj];
        float4 c1 = *(const float4*)&S[SGK_OFF + 8*tj + 4];
        float sg8[8] = {c0.x,c0.y,c0.z,c0.w,c1.x,c1.y,c1.z,c1.w};
        #pragma unroll
        for (int cc = 0; cc < 8; ++cc) {
            ff2 gs; gs.x = sg8[cc]; gs.y = sg8[cc];
            acc2[cc][0] = (acc2[cc][0] * sq0) * gs;
            acc2[cc][1] = (acc2[cc][1] * sq1) * gs;
        }
    }

    // ---- row max: local over 8 cols then DPP 8-group reduce (VALU-only) -----
    float m4[4];
    #pragma unroll
    for (int rr = 0; rr < 4; ++rr) {
        float mp = -1e30f;
        #pragma unroll
        for (int cc = 0; cc < 8; ++cc) mp = fmaxf(mp, acc2[cc][rr >> 1][rr & 1]);
        m4[rr] = max8_dpp(mp);
    }

    // ---- exp, Z via DPP ascending prefix (exact assoc) + 1 broadcast/row ----
    float z4[4];
    #pragma unroll
    for (int rr = 0; rr < 4; ++rr) {
        float zp = 0.f;
        #pragma unroll
        for (int cc = 0; cc < 8; ++cc) {
            float ss = acc2[cc][rr >> 1][rr & 1];
            float e = __expf(ss - m4[rr]);
            zp += e;
            acc2[cc][rr >> 1][rr & 1] = (ss > theta) ? e : 0.f;
        }
        float zpre = prefix8_asc(zp);
        z4[rr] = __shfl(zpre, gb + 7, 64);
    }

    // ---- stage A pass 0 (cols j 0..31) into own [32 j][32 i] half -----------
    // Rotation depends on jl>>3 (= writer's tj&3): conflict-free (R5-R9: 0).
    float* Aw = &S[A_OFF + 1024*wv];
    if ((tj >> 2) == 0) {
        #pragma unroll
        for (int cc = 0; cc < 8; ++cc) {
            const int jl = 8*(tj & 3) + cc;
            *(float4*)&Aw[jl*32 + ((4*rg + 4*(jl >> 3)) & 31)] =
                make_float4(acc2[cc][0].x, acc2[cc][0].y, acc2[cc][1].x, acc2[cc][1].y);
        }
    }
    __syncthreads();   // B3: V complete (cross-wave); A pass-0 staged

    // ============ AV: lane = (rg, dg); rows 32*wv+4*rg..+4, d 4*dgc..+4 ======
    const int dg  = tj;
    const int dgc = (dg < 7) ? dg : 6;   // dg==7 duplicates dg==6, write masked
    ff2 pv[4][2];                         // pv[rr][p][e]: d-chunk elem 2p+e
    #pragma unroll
    for (int rr = 0; rr < 4; ++rr) {
        pv[rr][0] = (ff2){0.f, 0.f};
        pv[rr][1] = (ff2){0.f, 0.f};
    }

    #pragma unroll 8
    for (int jl = 0; jl < 32; ++jl) {
        float4 a4 = *(const float4*)&Aw[jl*32 + ((4*rg + 4*(jl >> 3)) & 31)];
        float4 v4 = *(const float4*)&S[V_OFF + jl*C + 4*dgc];
        ff2 vlo; vlo.x = v4.x; vlo.y = v4.y;
        ff2 vhi; vhi.x = v4.z; vhi.y = v4.w;
        float a8[4] = {a4.x, a4.y, a4.z, a4.w};
        #pragma unroll
        for (int rr = 0; rr < 4; ++rr) {
            ff2 as; as.x = a8[rr]; as.y = a8[rr];
            pv[rr][0] += as * vlo;
            pv[rr][1] += as * vhi;
        }
    }

    // ---- stage A pass 1 (cols j 32..63), overwrite own half (in-wave order) --
    if ((tj >> 2) == 1) {
        #pragma unroll
        for (int cc = 0; cc < 8; ++cc) {
            const int jl = 8*(tj & 3) + cc;
            *(float4*)&Aw[jl*32 + ((4*rg + 4*(jl >> 3)) & 31)] =
                make_float4(acc2[cc][0].x, acc2[cc][0].y, acc2[cc][1].x, acc2[cc][1].y);
        }
    }

    #pragma unroll 8
    for (int jl = 0; jl < 32; ++jl) {
        float4 a4 = *(const float4*)&Aw[jl*32 + ((4*rg + 4*(jl >> 3)) & 31)];
        float4 v4 = *(const float4*)&S[V_OFF + (32 + jl)*C + 4*dgc];
        ff2 vlo; vlo.x = v4.x; vlo.y = v4.y;
        ff2 vhi; vhi.x = v4.z; vhi.y = v4.w;
        float a8[4] = {a4.x, a4.y, a4.z, a4.w};
        #pragma unroll
        for (int rr = 0; rr < 4; ++rr) {
            ff2 as; as.x = a8[rr]; as.y = a8[rr];
            pv[rr][0] += as * vlo;
            pv[rr][1] += as * vhi;
        }
    }

    // normalize by Z (exact 1.0f/Z divide; z4 lives in this lane)
    #pragma unroll
    for (int rr = 0; rr < 4; ++rr) {
        float rz = 1.0f / z4[rr];
        ff2 rz2; rz2.x = rz; rz2.y = rz;
        pv[rr][0] *= rz2;
        pv[rr][1] *= rz2;
    }

    // ---- OT: overlay own A half (all own-A reads done; in-wave order) -------
    if (dg < 7) {
        #pragma unroll
        for (int rr = 0; rr < 4; ++rr)
            *(float4*)&Aw[(4*rg+rr)*C + 4*dg] =
                make_float4(pv[rr][0].x, pv[rr][0].y, pv[rr][1].x, pv[rr][1].y);
    }
    // NO barrier: epilogue below reads only THIS wave's OT region (in-wave
    // DS producer/consumer ordering, same pattern as the A staging -> AV
    // reads used since R3). B4 deleted.

    // ====== epilogue: WAVE-LOCAL. lane = (own token tk, e-half eh) ===========
    const int tk  = ln & 31;           // token within own 32 rows
    const int eh  = ln >> 5;           // e-half: 0 -> e 0..15, 1 -> e 16..27
    const int tok = 32*wv + tk;
    const int ob0 = tok >> 3, ob1 = tok & 7;
    const size_t obase = ((((size_t)Bi * 256) + (size_t)(hw * 8 + ob0)) * 256
                          + (size_t)(ww * 8 + ob1)) * C;
    float o[C];
    {
        const float* orow = &S[A_OFF + 1024*wv + tk*C];
        #pragma unroll
        for (int i = 0; i < 7; ++i) {
            float4 t = *(const float4*)(orow + 4*i);
            o[4*i+0] = t.x; o[4*i+1] = t.y; o[4*i+2] = t.z; o[4*i+3] = t.w;
        }
    }
    if (eh == 0) {       // e = 0..15
        float y[16];
        #pragma unroll 2
        for (int e4 = 0; e4 < 4; ++e4) {
            #pragma unroll
            for (int t = 0; t < 4; ++t) {
                const int e = 4*e4 + t;
                ff2 a = {0.f, 0.f};
                #pragma unroll
                for (int d = 0; d < C; d += 2) {
                    ff2 w = *(const ff2*)&Wout[e*C + d];
                    ff2 ov; ov.x = o[d]; ov.y = o[d+1];
                    a += w * ov;
                }
                y[e] = (a.x + a.y) + bout[e];
            }
        }
        float4* yp = (float4*)(out + obase);
        #pragma unroll
        for (int i = 0; i < 4; ++i)
            yp[i] = make_float4(y[4*i+0], y[4*i+1], y[4*i+2], y[4*i+3]);
    } else {             // e = 16..27
        float y[12];
        #pragma unroll 2
        for (int e4 = 0; e4 < 3; ++e4) {
            #pragma unroll
            for (int t = 0; t < 4; ++t) {
                const int e = 16 + 4*e4 + t;
                ff2 a = {0.f, 0.f};
                #pragma unroll
                for (int d = 0; d < C; d += 2) {
                    ff2 w = *(const ff2*)&Wout[e*C + d];
                    ff2 ov; ov.x = o[d]; ov.y = o[d+1];
                    a += w * ov;
                }
                y[4*e4+t] = (a.x + a.y) + bout[e];
            }
        }
        float4* yp = (float4*)(out + obase + 16);
        #pragma unroll
        for (int i = 0; i < 3; ++i)
            yp[i] = make_float4(y[4*i+0], y[4*i+1], y[4*i+2], y[4*i+3]);
    }
}

extern "C" void kernel_launch(void* const* d_in, const int* in_sizes, int n_in,
                              void* d_out, int out_size, void* d_ws, size_t ws_size,
                              hipStream_t stream) {
    const float* x     = (const float*)d_in[0];
    const float* W_qk  = (const float*)d_in[1];
    const float* W_v   = (const float*)d_in[2];
    const float* W_out = (const float*)d_in[3];
    const float* b_out = (const float*)d_in[4];
    const float* W_pcq = (const float*)d_in[5];
    const float* b_pcq = (const float*)d_in[6];
    const float* W_pck = (const float*)d_in[7];
    const float* b_pck = (const float*)d_in[8];
    const float* W_m1  = (const float*)d_in[9];
    const float* W_m2a = (const float*)d_in[10];
    const float* W_m2b = (const float*)d_in[11];
    float* y = (float*)d_out;

    // 8192 problems, one 128-thread (2-wave) block per problem
    hipLaunchKernelGGL(fa_tiled, dim3(8192), dim3(128), 0, stream,
                       x, W_qk, W_v, W_out, b_out, W_pcq, b_pcq,
                       W_pck, b_pck, W_m1, W_m2a, W_m2b, y);
}

// Round 12
// 215.719 us; speedup vs baseline: 1.0415x; 1.0205x over previous
//
#include <hip/hip_runtime.h>
#include <math.h>

#define C 28   // channels == dim_head == rank
#define N 64   // tokens per window (8x8)

typedef float ff2 __attribute__((ext_vector_type(2)));

// LDS layout (float offsets). 4032 floats = 16128 B -> 10 blocks/CU by LDS.
// Phase 1: QT [28][64] @0, KT [28][64] @1792 (dead after B2)
// Phase 2: A = per-wave [32 j][32 i] halves @0/@1024 (overlay QT), staged twice
//          V [64][28] @2048 (overlays dead KT tail; written AFTER B2 from regs)
//          OT = per-wave [32][28] overlays own A after final AV reads
// Scalars SQ/SGK/TH at 3840+ (outside all overlay ranges).
// This is the R9 configuration -- best measured (130-134 us dispatch) -- with
// the B4 barrier and cross-wave token-parallel epilogue restored (R11's
// barrier-free wave-local epilogue measured neutral-to-worse).
#define A_OFF   0
#define QT_OFF  0
#define KT_OFF  1792
#define V_OFF   2048
#define SQ_OFF  3840
#define SGK_OFF 3904
#define TH_OFF  3968
#define LDS_FLOATS 4032

// Exact ascending 8-lane-group prefix sum via DPP row_shr:1 (VALU-only).
// Lane gb+7 holds the fully left-nested ascending sum (validated R6-R11).
__device__ __forceinline__ float prefix8_asc(float s) {
    float p = s;
    #pragma unroll
    for (int k = 0; k < 7; ++k) {
        int sh = __builtin_amdgcn_update_dpp(0, __float_as_int(p),
                                             0x111 /*row_shr:1*/, 0xF, 0xF, true);
        p = __int_as_float(sh) + s;
    }
    return p;
}

// Max over each 8-lane group, VALU-only (validated R8-R11).
__device__ __forceinline__ float max8_dpp(float m) {
    int t;
    t = __builtin_amdgcn_update_dpp(0, __float_as_int(m), 0xB1,  0xF, 0xF, true);
    m = fmaxf(m, __int_as_float(t));
    t = __builtin_amdgcn_update_dpp(0, __float_as_int(m), 0x4E,  0xF, 0xF, true);
    m = fmaxf(m, __int_as_float(t));
    t = __builtin_amdgcn_update_dpp(0, __float_as_int(m), 0x141, 0xF, 0xF, true);
    m = fmaxf(m, __int_as_float(t));
    return m;
}

__global__ __launch_bounds__(128, 8)   // hard-pin VGPR <= 512/8 = 64 (granule)
void fa_tiled(const float* __restrict__ x,
              const float* __restrict__ Wqk,   // [56][28]
              const float* __restrict__ Wv,    // [28][28]
              const float* __restrict__ Wout,  // [28][28]
              const float* __restrict__ bout,  // [28]
              const float* __restrict__ Wpcq,  // [28]
              const float* __restrict__ bpcq,  // [1]
              const float* __restrict__ Wpck,  // [28]
              const float* __restrict__ bpck,  // [1]
              const float* __restrict__ Wm1,   // [64]
              const float* __restrict__ Wm2a,  // [64][64]
              const float* __restrict__ Wm2b,  // [64]
              float* __restrict__ out)
{
    __shared__ float S[LDS_FLOATS];

    const int tid = threadIdx.x;       // 0..127 (2 waves per problem)
    const int wv  = tid >> 6;          // wave id: 0 -> q-side, 1 -> k-side
    const int ln  = tid & 63;          // lane in wave == token id in phase A
    const int pid = blockIdx.x;        // 0..8191, one block per problem
    const int win = pid >> 3;
    const int Bi  = pid & 7;
    const int hw = win >> 5, ww = win & 31;
    const int b0 = ln >> 3, b1 = ln & 7;
    const size_t base = ((((size_t)Bi * 256) + (size_t)(hw * 8 + b0)) * 256
                         + (size_t)(ww * 8 + b1)) * C;

    // sim tile coords: 4 rows x 8 cols per lane
    const int ti = tid >> 3;           // 0..15 (global row group)
    const int tj = tid & 7;            // 0..7  (col group, j = 8*tj+cc)
    const int rg = ti & 7;             // wave-local row group 0..7
    const int gb = ln & 56;            // in-wave base of this lane's tj-group

    float vv[16];                      // deferred V values (wave0:16, wave1:12)

    // ========== Phase A (validated ff2): q/k proj + V-into-regs =============
    {
        float xr[C];
        {
            const float4* p = (const float4*)(x + base);
            #pragma unroll
            for (int i = 0; i < 7; ++i) {
                float4 t = p[i];
                xr[4*i+0] = t.x; xr[4*i+1] = t.y; xr[4*i+2] = t.z; xr[4*i+3] = t.w;
            }
        }

        if (wv == 0) {
            // q -> QT (transposed), sig_q. ff2 pairs = (even,odd) chains.
            ff2 sq2 = {0.f, 0.f};
            #pragma unroll 2
            for (int d4 = 0; d4 < 7; ++d4) {
                float qq[4];
                #pragma unroll
                for (int t = 0; t < 4; ++t) {
                    const int d = 4*d4 + t;
                    ff2 a = {0.f, 0.f};
                    #pragma unroll
                    for (int c = 0; c < C; c += 2) {
                        ff2 w = *(const ff2*)&Wqk[d*C + c];
                        ff2 xv; xv.x = xr[c]; xv.y = xr[c+1];
                        a += w * xv;
                    }
                    qq[t] = a.x + a.y;
                    S[QT_OFF + d*64 + ln] = qq[t];
                }
                ff2 q01; q01.x = qq[0]; q01.y = qq[1];
                ff2 q23; q23.x = qq[2]; q23.y = qq[3];
                ff2 w01 = *(const ff2*)&Wpcq[4*d4];
                ff2 w23 = *(const ff2*)&Wpcq[4*d4+2];
                sq2 += q01 * w01;
                sq2 += q23 * w23;
            }
            S[SQ_OFF + ln] = sq2.x + sq2.y + bpcq[0];
            // V dims d = 0..15 into regs
            #pragma unroll
            for (int d4 = 0; d4 < 4; ++d4) {
                #pragma unroll
                for (int t = 0; t < 4; ++t) {
                    const int d = 4*d4 + t;
                    ff2 a = {0.f, 0.f};
                    #pragma unroll
                    for (int c = 0; c < C; c += 2) {
                        ff2 w = *(const ff2*)&Wv[d*C + c];
                        ff2 xv; xv.x = xr[c]; xv.y = xr[c+1];
                        a += w * xv;
                    }
                    vv[4*d4+t] = a.x + a.y;
                }
            }
        } else {
            // k -> KT (transposed), sig_k (ak chain scalar-sequential: exact).
            float ak = 0.f;
            #pragma unroll 2
            for (int d4 = 0; d4 < 7; ++d4) {
                float kk[4];
                #pragma unroll
                for (int t = 0; t < 4; ++t) {
                    const int d = 4*d4 + t;
                    ff2 a = {0.f, 0.f};
                    #pragma unroll
                    for (int c = 0; c < C; c += 2) {
                        ff2 w = *(const ff2*)&Wqk[(C+d)*C + c];
                        ff2 xv; xv.x = xr[c]; xv.y = xr[c+1];
                        a += w * xv;
                    }
                    kk[t] = a.x + a.y;
                    S[KT_OFF + d*64 + ln] = kk[t];
                }
                ak += kk[0] * Wpck[4*d4+0];
                ak += kk[1] * Wpck[4*d4+1];
                ak += kk[2] * Wpck[4*d4+2];
                ak += kk[3] * Wpck[4*d4+3];
            }
            S[SGK_OFF + ln] = ak + bpck[0];
            // V dims d = 16..27 into regs
            #pragma unroll
            for (int d4 = 4; d4 < 7; ++d4) {
                #pragma unroll
                for (int t = 0; t < 4; ++t) {
                    const int d = 4*d4 + t;
                    ff2 a = {0.f, 0.f};
                    #pragma unroll
                    for (int c = 0; c < C; c += 2) {
                        ff2 w = *(const ff2*)&Wv[d*C + c];
                        ff2 xv; xv.x = xr[c]; xv.y = xr[c+1];
                        a += w * xv;
                    }
                    vv[4*(d4-4)+t] = a.x + a.y;
                }
            }
        }
    }
    __syncthreads();   // B1: QT, KT, SQ, SGK ready

    // ====== sim: 4x8 tile as ff2 row-pairs (validated, bit-exact) ===========
    ff2 acc2[8][2];    // acc2[cc][p][e] = sraw[4ti + 2p+e][8tj+cc]
    #pragma unroll
    for (int cc = 0; cc < 8; ++cc) {
        acc2[cc][0] = (ff2){0.f, 0.f};
        acc2[cc][1] = (ff2){0.f, 0.f};
    }

    #pragma unroll 2
    for (int d = 0; d < C; ++d) {
        float4 qa = *(const float4*)&S[QT_OFF + d*64 + 4*ti];
        float4 ka = *(const float4*)&S[KT_OFF + d*64 + 8*tj];
        float4 kb = *(const float4*)&S[KT_OFF + d*64 + 8*tj + 4];
        ff2 q0; q0.x = qa.x; q0.y = qa.y;
        ff2 q1; q1.x = qa.z; q1.y = qa.w;
        float k8[8] = {ka.x,ka.y,ka.z,ka.w,kb.x,kb.y,kb.z,kb.w};
        #pragma unroll
        for (int cc = 0; cc < 8; ++cc) {
            ff2 ks; ks.x = k8[cc]; ks.y = k8[cc];
            acc2[cc][0] += q0 * ks;
            acc2[cc][1] += q1 * ks;
        }
    }

    // ---- theta partials (strict ascending j per 8-col group; diag excluded),
    //      DPP ascending prefix (exact assoc); lane tj==7 writes all 4 as b128
    {
        float4 wa = *(const float4*)&Wm1[8*tj];
        float4 wb = *(const float4*)&Wm1[8*tj + 4];
        float w8[8] = {wa.x,wa.y,wa.z,wa.w,wb.x,wb.y,wb.z,wb.w};
        const bool e0 = (4*ti == 8*tj);          // diag at cc == rr
        const bool e4 = (4*ti - 8*tj == 4);      // diag at cc == rr+4
        float th4[4];
        #pragma unroll
        for (int rr = 0; rr < 4; ++rr) {
            float s = 0.f;
            #pragma unroll
            for (int cc = 0; cc < 8; ++cc) {
                float av = acc2[cc][rr >> 1][rr & 1];
                float term = av * w8[cc];
                if (cc == rr     && e0) term = 0.f;
                if (cc == rr + 4 && e4) term = 0.f;
                s += term;
            }
            th4[rr] = prefix8_asc(s);
        }
        if (tj == 7)
            *(float4*)&S[TH_OFF + 4*ti] =
                make_float4(th4[0], th4[1], th4[2], th4[3]);
    }
    __syncthreads();   // B2: QT/KT reads done, TH complete

    // ---- V write (deferred; overlays dead KT tail). Cross-wave: B3 guards ----
    if (wv == 0) {
        *(float4*)&S[V_OFF + ln*C +  0] = make_float4(vv[0], vv[1], vv[2], vv[3]);
        *(float4*)&S[V_OFF + ln*C +  4] = make_float4(vv[4], vv[5], vv[6], vv[7]);
        *(float4*)&S[V_OFF + ln*C +  8] = make_float4(vv[8], vv[9], vv[10],vv[11]);
        *(float4*)&S[V_OFF + ln*C + 12] = make_float4(vv[12],vv[13],vv[14],vv[15]);
    } else {
        *(float4*)&S[V_OFF + ln*C + 16] = make_float4(vv[0], vv[1], vv[2], vv[3]);
        *(float4*)&S[V_OFF + ln*C + 20] = make_float4(vv[4], vv[5], vv[6], vv[7]);
        *(float4*)&S[V_OFF + ln*C + 24] = make_float4(vv[8], vv[9], vv[10],vv[11]);
    }

    // ---- MLP2 (validated ff2; both waves redundantly -> identical theta) ----
    float theta;
    {
        const float* wrow = Wm2a + ln * N;
        ff2 A = {0.f, 0.f}, B = {0.f, 0.f};
        #pragma unroll 4
        for (int i4 = 0; i4 < 16; ++i4) {
            float4 t4 = *(const float4*)&S[TH_OFF + 4*i4];
            float4 w4 = *(const float4*)&wrow[4*i4];
            ff2 tl; tl.x = t4.x; tl.y = t4.y;
            ff2 th; th.x = t4.z; th.y = t4.w;
            ff2 wl; wl.x = w4.x; wl.y = w4.y;
            ff2 wh; wh.x = w4.z; wh.y = w4.w;
            A += tl * wl;
            B += th * wh;
        }
        float t = (A.x + A.y) + (B.x + B.y);
        t = (t >= 0.f) ? t : 0.1f * t;
        theta = t * Wm2b[ln];
        #pragma unroll
        for (int off = 32; off > 0; off >>= 1)
            theta += __shfl_xor(theta, off, 64);
    }

    // ---- Sigma scale (order matches: (sraw*sq)*sgk), element-wise exact -----
    {
        float4 a = *(const float4*)&S[SQ_OFF + 4*ti];
        ff2 sq0; sq0.x = a.x; sq0.y = a.y;
        ff2 sq1; sq1.x = a.z; sq1.y = a.w;
        float4 c0 = *(const float4*)&S[SGK_OFF + 8*tj];
        float4 c1 = *(const float4*)&S[SGK_OFF + 8*tj + 4];
        float sg8[8] = {c0.x,c0.y,c0.z,c0.w,c1.x,c1.y,c1.z,c1.w};
        #pragma unroll
        for (int cc = 0; cc < 8; ++cc) {
            ff2 gs; gs.x = sg8[cc]; gs.y = sg8[cc];
            acc2[cc][0] = (acc2[cc][0] * sq0) * gs;
            acc2[cc][1] = (acc2[cc][1] * sq1) * gs;
        }
    }

    // ---- row max: local over 8 cols then DPP 8-group reduce (VALU-only) -----
    float m4[4];
    #pragma unroll
    for (int rr = 0; rr < 4; ++rr) {
        float mp = -1e30f;
        #pragma unroll
        for (int cc = 0; cc < 8; ++cc) mp = fmaxf(mp, acc2[cc][rr >> 1][rr & 1]);
        m4[rr] = max8_dpp(mp);
    }

    // ---- exp, Z via DPP ascending prefix (exact assoc) + 1 broadcast/row ----
    float z4[4];
    #pragma unroll
    for (int rr = 0; rr < 4; ++rr) {
        float zp = 0.f;
        #pragma unroll
        for (int cc = 0; cc < 8; ++cc) {
            float ss = acc2[cc][rr >> 1][rr & 1];
            float e = __expf(ss - m4[rr]);
            zp += e;
            acc2[cc][rr >> 1][rr & 1] = (ss > theta) ? e : 0.f;
        }
        float zpre = prefix8_asc(zp);
        z4[rr] = __shfl(zpre, gb + 7, 64);
    }

    // ---- stage A pass 0 (cols j 0..31) into own [32 j][32 i] half -----------
    // Rotation depends on jl>>3 (= writer's tj&3): conflict-free (R5-R9: 0).
    float* Aw = &S[A_OFF + 1024*wv];
    if ((tj >> 2) == 0) {
        #pragma unroll
        for (int cc = 0; cc < 8; ++cc) {
            const int jl = 8*(tj & 3) + cc;
            *(float4*)&Aw[jl*32 + ((4*rg + 4*(jl >> 3)) & 31)] =
                make_float4(acc2[cc][0].x, acc2[cc][0].y, acc2[cc][1].x, acc2[cc][1].y);
        }
    }
    __syncthreads();   // B3: V complete (cross-wave); A pass-0 staged

    // ============ AV: lane = (rg, dg); rows 32*wv+4*rg..+4, d 4*dgc..+4 ======
    const int dg  = tj;
    const int dgc = (dg < 7) ? dg : 6;   // dg==7 duplicates dg==6, write masked
    ff2 pv[4][2];                         // pv[rr][p][e]: d-chunk elem 2p+e
    #pragma unroll
    for (int rr = 0; rr < 4; ++rr) {
        pv[rr][0] = (ff2){0.f, 0.f};
        pv[rr][1] = (ff2){0.f, 0.f};
    }

    #pragma unroll 8
    for (int jl = 0; jl < 32; ++jl) {
        float4 a4 = *(const float4*)&Aw[jl*32 + ((4*rg + 4*(jl >> 3)) & 31)];
        float4 v4 = *(const float4*)&S[V_OFF + jl*C + 4*dgc];
        ff2 vlo; vlo.x = v4.x; vlo.y = v4.y;
        ff2 vhi; vhi.x = v4.z; vhi.y = v4.w;
        float a8[4] = {a4.x, a4.y, a4.z, a4.w};
        #pragma unroll
        for (int rr = 0; rr < 4; ++rr) {
            ff2 as; as.x = a8[rr]; as.y = a8[rr];
            pv[rr][0] += as * vlo;
            pv[rr][1] += as * vhi;
        }
    }

    // ---- stage A pass 1 (cols j 32..63), overwrite own half (in-wave order) --
    if ((tj >> 2) == 1) {
        #pragma unroll
        for (int cc = 0; cc < 8; ++cc) {
            const int jl = 8*(tj & 3) + cc;
            *(float4*)&Aw[jl*32 + ((4*rg + 4*(jl >> 3)) & 31)] =
                make_float4(acc2[cc][0].x, acc2[cc][0].y, acc2[cc][1].x, acc2[cc][1].y);
        }
    }

    #pragma unroll 8
    for (int jl = 0; jl < 32; ++jl) {
        float4 a4 = *(const float4*)&Aw[jl*32 + ((4*rg + 4*(jl >> 3)) & 31)];
        float4 v4 = *(const float4*)&S[V_OFF + (32 + jl)*C + 4*dgc];
        ff2 vlo; vlo.x = v4.x; vlo.y = v4.y;
        ff2 vhi; vhi.x = v4.z; vhi.y = v4.w;
        float a8[4] = {a4.x, a4.y, a4.z, a4.w};
        #pragma unroll
        for (int rr = 0; rr < 4; ++rr) {
            ff2 as; as.x = a8[rr]; as.y = a8[rr];
            pv[rr][0] += as * vlo;
            pv[rr][1] += as * vhi;
        }
    }

    // normalize by Z (exact 1.0f/Z divide; z4 lives in this lane)
    #pragma unroll
    for (int rr = 0; rr < 4; ++rr) {
        float rz = 1.0f / z4[rr];
        ff2 rz2; rz2.x = rz; rz2.y = rz;
        pv[rr][0] *= rz2;
        pv[rr][1] *= rz2;
    }

    // ---- OT: overlay own A half (all own-A reads done; in-wave order) -------
    if (dg < 7) {
        #pragma unroll
        for (int rr = 0; rr < 4; ++rr)
            *(float4*)&Aw[(4*rg+rr)*C + 4*dg] =
                make_float4(pv[rr][0].x, pv[rr][0].y, pv[rr][1].x, pv[rr][1].y);
    }
    __syncthreads();   // B4: both OT halves ready

    // ====== epilogue (validated ff2): out projection, e-split by wave ========
    float o[C];
    {
        const float* orow = &S[A_OFF + 1024*(ln >> 5) + (ln & 31)*C];
        #pragma unroll
        for (int i = 0; i < 7; ++i) {
            float4 t = *(const float4*)(orow + 4*i);
            o[4*i+0] = t.x; o[4*i+1] = t.y; o[4*i+2] = t.z; o[4*i+3] = t.w;
        }
    }
    if (wv == 0) {       // e = 0..15
        float y[16];
        #pragma unroll 2
        for (int e4 = 0; e4 < 4; ++e4) {
            #pragma unroll
            for (int t = 0; t < 4; ++t) {
                const int e = 4*e4 + t;
                ff2 a = {0.f, 0.f};
                #pragma unroll
                for (int d = 0; d < C; d += 2) {
                    ff2 w = *(const ff2*)&Wout[e*C + d];
                    ff2 ov; ov.x = o[d]; ov.y = o[d+1];
                    a += w * ov;
                }
                y[e] = (a.x + a.y) + bout[e];
            }
        }
        float4* yp = (float4*)(out + base);
        #pragma unroll
        for (int i = 0; i < 4; ++i)
            yp[i] = make_float4(y[4*i+0], y[4*i+1], y[4*i+2], y[4*i+3]);
    } else {             // e = 16..27
        float y[12];
        #pragma unroll 2
        for (int e4 = 0; e4 < 3; ++e4) {
            #pragma unroll
            for (int t = 0; t < 4; ++t) {
                const int e = 16 + 4*e4 + t;
                ff2 a = {0.f, 0.f};
                #pragma unroll
                for (int d = 0; d < C; d += 2) {
                    ff2 w = *(const ff2*)&Wout[e*C + d];
                    ff2 ov; ov.x = o[d]; ov.y = o[d+1];
                    a += w * ov;
                }
                y[4*e4+t] = (a.x + a.y) + bout[e];
            }
        }
        float4* yp = (float4*)(out + base + 16);
        #pragma unroll
        for (int i = 0; i < 3; ++i)
            yp[i] = make_float4(y[4*i+0], y[4*i+1], y[4*i+2], y[4*i+3]);
    }
}

extern "C" void kernel_launch(void* const* d_in, const int* in_sizes, int n_in,
                              void* d_out, int out_size, void* d_ws, size_t ws_size,
                              hipStream_t stream) {
    const float* x     = (const float*)d_in[0];
    const float* W_qk  = (const float*)d_in[1];
    const float* W_v   = (const float*)d_in[2];
    const float* W_out = (const float*)d_in[3];
    const float* b_out = (const float*)d_in[4];
    const float* W_pcq = (const float*)d_in[5];
    const float* b_pcq = (const float*)d_in[6];
    const float* W_pck = (const float*)d_in[7];
    const float* b_pck = (const float*)d_in[8];
    const float* W_m1  = (const float*)d_in[9];
    const float* W_m2a = (const float*)d_in[10];
    const float* W_m2b = (const float*)d_in[11];
    float* y = (float*)d_out;

    // 8192 problems, one 128-thread (2-wave) block per problem
    hipLaunchKernelGGL(fa_tiled, dim3(8192), dim3(128), 0, stream,
                       x, W_qk, W_v, W_out, b_out, W_pcq, b_pcq,
                       W_pck, b_pck, W_m1, W_m2a, W_m2b, y);
}